// Round 1
// baseline (464.968 us; speedup 1.0000x reference)
//
#include <hip/hip_runtime.h>
#include <math.h>

#define SEQ_LEN   720
#define IN_LEN    360
#define PRED_LEN  336
#define CHANNELS  862
#define RANK      32
#define BATCH     256

// ws layout (floats):
//   Wp   [360][32]  at 0       (folded DCT^T @ A, scaled by 1/(360*sqrt(2)))
//   csw  [32]       at 11520   (column sums of Wp)
//   Vt   [336][32]  at 11552   (transposed B @ M_IDCT)
//   cvec [336]      at 22304   (b @ M_IDCT)
#define WS_WP    0
#define WS_CSW   11520
#define WS_VT    11552
#define WS_CVEC  22304

// ---------------- precompute kernels (run every launch; ~us scale) ----------

// Wp[n][r] = (1/(360*sqrt(2))) * sum_k D[k][n] * A[k][r]
// D[k][n] = coef_k * cos(pi * k*(2n+1) / 720), coef_0 = 1/sqrt(360), coef_k = 2/sqrt(720)
__global__ __launch_bounds__(256) void k_prep_w(const float* __restrict__ A,
                                                float* __restrict__ Wp) {
    __shared__ float sA[IN_LEN * RANK];              // 46080 B, direct copy [k][r]
    for (int i = threadIdx.x; i < IN_LEN * RANK; i += 256) sA[i] = A[i];
    __syncthreads();

    int idx = blockIdx.x * 256 + threadIdx.x;        // 45*256 == 11520 exactly
    int n = idx >> 5, r = idx & 31;
    int step = 2 * n + 1;
    int m = 0;                                       // k*(2n+1) mod 1440 (period of cos)
    float sum = 0.f;
    for (int k = 0; k < IN_LEN; ++k) {
        float coef = (k == 0) ? 0.05270462766947299f   // 1/sqrt(360)
                              : 0.07453559924999299f;  // 2/sqrt(720)
        float d = coef * cospif((float)m * (1.0f / 720.0f));
        sum = fmaf(d, sA[k * RANK + r], sum);
        m += step; if (m >= 1440) m -= 1440;
    }
    Wp[idx] = sum * 0.0019641855032960957f;          // (1/sqrt(2)) / 360
}

// csw[r] = sum_n Wp[n][r]
__global__ void k_colsum(const float* __restrict__ Wp, float* __restrict__ csw) {
    int r = threadIdx.x;
    if (r >= RANK) return;
    float s = 0.f;
    for (int n = 0; n < IN_LEN; ++n) s += Wp[n * RANK + r];
    csw[r] = s;
}

// Vt[n][r] = sum_k B[r][k] * M[k][n];  cvec[n] = sum_k b[k] * M[k][n]
// M[k][n] = cos(pi * k*(2n+1) / 672) / 336, row k=0 halved.
__global__ __launch_bounds__(256) void k_prep_v(const float* __restrict__ B,
                                                const float* __restrict__ bias,
                                                float* __restrict__ Vt,
                                                float* __restrict__ cvec) {
    int idx = blockIdx.x * 256 + threadIdx.x;
    if (blockIdx.x < 42) {                            // 42*256 == 10752 == 336*32 exactly
        __shared__ float sBt[PRED_LEN * RANK];        // B transposed -> [k][r], conflict-free reads
        for (int i = threadIdx.x; i < PRED_LEN * RANK; i += 256) {
            int r = i / PRED_LEN, k = i - r * PRED_LEN;
            sBt[k * RANK + r] = B[i];
        }
        __syncthreads();
        int n = idx >> 5, r = idx & 31;
        int step = 2 * n + 1, m = 0;                  // k*(2n+1) mod 1344
        float sum = 0.f;
        for (int k = 0; k < PRED_LEN; ++k) {
            float mk = cospif((float)m * (1.0f / 672.0f));
            if (k == 0) mk *= 0.5f;
            sum = fmaf(mk, sBt[k * RANK + r], sum);
            m += step; if (m >= 1344) m -= 1344;
        }
        Vt[n * RANK + r] = sum * (1.0f / 336.0f);
    } else {
        int n = idx - PRED_LEN * RANK;
        if (n < PRED_LEN) {
            int step = 2 * n + 1, m = 0;
            float sum = 0.f;
            for (int k = 0; k < PRED_LEN; ++k) {
                float mk = cospif((float)m * (1.0f / 672.0f));
                if (k == 0) mk *= 0.5f;
                sum = fmaf(mk, bias[k], sum);
                m += step; if (m >= 1344) m -= 1344;
            }
            cvec[n] = sum * (1.0f / 336.0f);
        }
    }
}

// ---------------- fused main kernel -----------------------------------------
// One thread per (batch b, channel c).
// Stage 1: t[r] = sum_n (x[2n]+x[2n+1]) * Wp[n][r]  (Haar pair shares W row)
//          S    = sum of all x -> mean = S/720; t[r] -= S*csw[r]/360
// Stage 2: out[b][n][c] = sum_r t[r]*Vt[n][r] + cvec[n] + mean
__global__ __launch_bounds__(256) void k_main(const float* __restrict__ x,
                                              const float* __restrict__ Wp,
                                              const float* __restrict__ csw,
                                              const float* __restrict__ Vt,
                                              const float* __restrict__ cvec,
                                              float* __restrict__ out) {
    int c = blockIdx.x * 256 + threadIdx.x;
    int b = blockIdx.y;
    if (c >= CHANNELS) return;

    const float* xp = x + (size_t)b * (SEQ_LEN * CHANNELS) + c;

    float acc[RANK];
    #pragma unroll
    for (int r = 0; r < RANK; ++r) acc[r] = 0.f;
    float S = 0.f;

    for (int n = 0; n < IN_LEN; ++n) {
        float x0 = xp[0];
        float x1 = xp[CHANNELS];
        xp += 2 * CHANNELS;
        float p = x0 + x1;
        S += p;
        const float4* w = (const float4*)(Wp + n * RANK);   // wave-uniform address
        #pragma unroll
        for (int q = 0; q < 8; ++q) {
            float4 wv = w[q];
            acc[4 * q + 0] = fmaf(p, wv.x, acc[4 * q + 0]);
            acc[4 * q + 1] = fmaf(p, wv.y, acc[4 * q + 1]);
            acc[4 * q + 2] = fmaf(p, wv.z, acc[4 * q + 2]);
            acc[4 * q + 3] = fmaf(p, wv.w, acc[4 * q + 3]);
        }
    }

    // finalize t: subtract mean contribution
    #pragma unroll
    for (int q = 0; q < 8; ++q) {
        float4 cs = ((const float4*)csw)[q];
        acc[4 * q + 0] = fmaf(-S * (1.0f / 360.0f), cs.x, acc[4 * q + 0]);
        acc[4 * q + 1] = fmaf(-S * (1.0f / 360.0f), cs.y, acc[4 * q + 1]);
        acc[4 * q + 2] = fmaf(-S * (1.0f / 360.0f), cs.z, acc[4 * q + 2]);
        acc[4 * q + 3] = fmaf(-S * (1.0f / 360.0f), cs.w, acc[4 * q + 3]);
    }
    float mean = S * (1.0f / 720.0f);

    float* op = out + (size_t)b * (PRED_LEN * CHANNELS) + c;
    for (int n = 0; n < PRED_LEN; ++n) {
        const float4* v = (const float4*)(Vt + n * RANK);   // wave-uniform address
        float o0 = 0.f, o1 = 0.f, o2 = 0.f, o3 = 0.f;
        #pragma unroll
        for (int q = 0; q < 8; ++q) {
            float4 vv = v[q];
            o0 = fmaf(acc[4 * q + 0], vv.x, o0);
            o1 = fmaf(acc[4 * q + 1], vv.y, o1);
            o2 = fmaf(acc[4 * q + 2], vv.z, o2);
            o3 = fmaf(acc[4 * q + 3], vv.w, o3);
        }
        op[0] = (o0 + o1) + (o2 + o3) + cvec[n] + mean;
        op += CHANNELS;
    }
}

// ---------------- launcher ---------------------------------------------------

extern "C" void kernel_launch(void* const* d_in, const int* in_sizes, int n_in,
                              void* d_out, int out_size, void* d_ws, size_t ws_size,
                              hipStream_t stream) {
    (void)in_sizes; (void)n_in; (void)out_size; (void)ws_size;
    const float* x    = (const float*)d_in[0];
    const float* A    = (const float*)d_in[1];
    const float* B    = (const float*)d_in[2];
    const float* bias = (const float*)d_in[3];
    float* out = (float*)d_out;
    float* ws  = (float*)d_ws;

    float* Wp   = ws + WS_WP;
    float* csw  = ws + WS_CSW;
    float* Vt   = ws + WS_VT;
    float* cvec = ws + WS_CVEC;

    k_prep_w<<<dim3(45), dim3(256), 0, stream>>>(A, Wp);
    k_colsum<<<dim3(1), dim3(64), 0, stream>>>(Wp, csw);
    k_prep_v<<<dim3(44), dim3(256), 0, stream>>>(B, bias, Vt, cvec);

    k_main<<<dim3(4, BATCH), dim3(256), 0, stream>>>(x, Wp, csw, Vt, cvec, out);
}

// Round 2
// 323.686 us; speedup vs baseline: 1.4365x; 1.4365x over previous
//
#include <hip/hip_runtime.h>
#include <math.h>

#define SEQ_LEN   720
#define IN_LEN    360
#define PRED_LEN  336
#define CHANNELS  862
#define RANK      32
#define BATCH     256

// ws layout (float offsets)
#define WS_WP    0        // Wp  [360][32] = DCT^T@A folded, incl. 1/(360*sqrt2)
#define WS_VT    11520    // Vt  [336][32] = (B @ M_IDCT)^T
#define WS_CVEC  22272    // cvec[336]     = b @ M_IDCT

// ---------------- single prep kernel (89 blocks) -----------------------------
// blocks 0-44:  Wp[n][r] = (1/(360*sqrt2)) * sum_k D[k][n]*A[k][r]
// blocks 45-86: Vt[n][r] = (1/336) * sum_k Bt[k][r]*cos(pi*k*(2n+1)/672), k=0 halved
// blocks 87-88: cvec[n]
__global__ __launch_bounds__(256) void k_prep(const float* __restrict__ A,
                                              const float* __restrict__ B,
                                              const float* __restrict__ bias,
                                              float* __restrict__ Wp,
                                              float* __restrict__ Vt,
                                              float* __restrict__ cvec) {
    __shared__ float sbuf[IN_LEN * RANK];            // 46080 B
    int blk = blockIdx.x;
    if (blk < 45) {
        for (int i = threadIdx.x; i < IN_LEN * RANK; i += 256) sbuf[i] = A[i];
        __syncthreads();
        int idx = blk * 256 + threadIdx.x;           // 45*256 == 11520
        int n = idx >> 5, r = idx & 31;
        int step = 2 * n + 1, m = 0;                 // k*(2n+1) mod 1440
        float sum = 0.f;
        for (int k = 0; k < IN_LEN; ++k) {
            float coef = (k == 0) ? 0.05270462766947299f    // 1/sqrt(360)
                                  : 0.07453559924999299f;   // 2/sqrt(720)
            float d = coef * cospif((float)m * (1.0f / 720.0f));
            sum = fmaf(d, sbuf[k * RANK + r], sum);
            m += step; if (m >= 1440) m -= 1440;
        }
        Wp[idx] = sum * 0.0019641855032960957f;      // (1/sqrt2)/360
    } else if (blk < 87) {
        for (int i = threadIdx.x; i < PRED_LEN * RANK; i += 256) {
            int r = i / PRED_LEN, k = i - r * PRED_LEN;
            sbuf[k * RANK + r] = B[i];               // B transposed -> [k][r]
        }
        __syncthreads();
        int idx = (blk - 45) * 256 + threadIdx.x;    // 42*256 == 10752
        int n = idx >> 5, r = idx & 31;
        int step = 2 * n + 1, m = 0;                 // k*(2n+1) mod 1344
        float sum = 0.f;
        for (int k = 0; k < PRED_LEN; ++k) {
            float mk = cospif((float)m * (1.0f / 672.0f));
            if (k == 0) mk *= 0.5f;
            sum = fmaf(mk, sbuf[k * RANK + r], sum);
            m += step; if (m >= 1344) m -= 1344;
        }
        Vt[idx] = sum * (1.0f / 336.0f);
    } else {
        int n = (blk - 87) * 256 + threadIdx.x;
        if (n < PRED_LEN) {
            int step = 2 * n + 1, m = 0;
            float sum = 0.f;
            for (int k = 0; k < PRED_LEN; ++k) {
                float mk = cospif((float)m * (1.0f / 672.0f));
                if (k == 0) mk *= 0.5f;
                sum = fmaf(mk, bias[k], sum);
                m += step; if (m >= 1344) m -= 1344;
            }
            cvec[n] = sum * (1.0f / 336.0f);
        }
    }
}

// ---------------- fused main kernel ------------------------------------------
// 2 channels per thread. Phase 1: t = P@Wp - (S/360)*csw (csw[r]=A[0][r]/sqrt720),
// W read from LDS (broadcast). Phase 2: LDS re-staged with Vt+cvec, out stores.
__global__ __launch_bounds__(256, 2) void k_main(const float* __restrict__ x,
                                                 const float* __restrict__ A,
                                                 const float* __restrict__ Wp,
                                                 const float* __restrict__ Vt,
                                                 const float* __restrict__ cvec,
                                                 float* __restrict__ out) {
    __shared__ float lds[IN_LEN * RANK];             // 46080 B, reused in phase 2
    const int tid = threadIdx.x;
    const int b = blockIdx.y;
    const int c0 = 2 * (blockIdx.x * 256 + tid);
    const bool active = (c0 < CHANNELS);

    // ---- stage Wp into LDS ----
    {
        const float4* src = (const float4*)Wp;
        float4* dst = (float4*)lds;
        for (int i = tid; i < IN_LEN * RANK / 4; i += 256) dst[i] = src[i];
    }
    __syncthreads();

    float acc0[RANK], acc1[RANK];
    float S0 = 0.f, S1 = 0.f, mean0 = 0.f, mean1 = 0.f;

    if (active) {
        #pragma unroll
        for (int r = 0; r < RANK; ++r) { acc0[r] = 0.f; acc1[r] = 0.f; }

        const float* xp = x + (size_t)b * (SEQ_LEN * CHANNELS) + c0;
        #pragma unroll 2
        for (int n = 0; n < IN_LEN; ++n) {
            float2 a0 = *(const float2*)(xp + (2 * n)     * CHANNELS);
            float2 a1 = *(const float2*)(xp + (2 * n + 1) * CHANNELS);
            float p0 = a0.x + a1.x;
            float p1 = a0.y + a1.y;
            S0 += p0; S1 += p1;
            const float4* w = (const float4*)(lds + n * RANK);
            #pragma unroll
            for (int q = 0; q < 8; ++q) {
                float4 wv = w[q];
                acc0[4*q+0] = fmaf(p0, wv.x, acc0[4*q+0]);
                acc1[4*q+0] = fmaf(p1, wv.x, acc1[4*q+0]);
                acc0[4*q+1] = fmaf(p0, wv.y, acc0[4*q+1]);
                acc1[4*q+1] = fmaf(p1, wv.y, acc1[4*q+1]);
                acc0[4*q+2] = fmaf(p0, wv.z, acc0[4*q+2]);
                acc1[4*q+2] = fmaf(p1, wv.z, acc1[4*q+2]);
                acc0[4*q+3] = fmaf(p0, wv.w, acc0[4*q+3]);
                acc1[4*q+3] = fmaf(p1, wv.w, acc1[4*q+3]);
            }
        }

        // finalize: csw[r] = A[0][r] / sqrt(720); t -= (S/360)*csw
        float g0 = -S0 * (1.0f / 360.0f) * 0.037267799624996496f;
        float g1 = -S1 * (1.0f / 360.0f) * 0.037267799624996496f;
        #pragma unroll
        for (int q = 0; q < 8; ++q) {
            float4 a4 = ((const float4*)A)[q];       // A[0][0..31], wave-uniform
            acc0[4*q+0] = fmaf(g0, a4.x, acc0[4*q+0]);
            acc1[4*q+0] = fmaf(g1, a4.x, acc1[4*q+0]);
            acc0[4*q+1] = fmaf(g0, a4.y, acc0[4*q+1]);
            acc1[4*q+1] = fmaf(g1, a4.y, acc1[4*q+1]);
            acc0[4*q+2] = fmaf(g0, a4.z, acc0[4*q+2]);
            acc1[4*q+2] = fmaf(g1, a4.z, acc1[4*q+2]);
            acc0[4*q+3] = fmaf(g0, a4.w, acc0[4*q+3]);
            acc1[4*q+3] = fmaf(g1, a4.w, acc1[4*q+3]);
        }
        mean0 = S0 * (1.0f / 720.0f);
        mean1 = S1 * (1.0f / 720.0f);
    }
    __syncthreads();                                 // phase-1 LDS reads done

    // ---- re-stage LDS with Vt + cvec ----
    {
        const float4* src = (const float4*)Vt;
        float4* dst = (float4*)lds;
        for (int i = tid; i < PRED_LEN * RANK / 4; i += 256) dst[i] = src[i];
        const float4* src2 = (const float4*)cvec;
        float4* dst2 = (float4*)(lds + PRED_LEN * RANK);
        for (int i = tid; i < PRED_LEN / 4; i += 256) dst2[i] = src2[i];
    }
    __syncthreads();

    if (active) {
        float* op = out + (size_t)b * (PRED_LEN * CHANNELS) + c0;
        for (int n = 0; n < PRED_LEN; ++n) {
            const float4* v = (const float4*)(lds + n * RANK);
            float o0a = 0.f, o0b = 0.f, o0c = 0.f, o0d = 0.f;
            float o1a = 0.f, o1b = 0.f, o1c = 0.f, o1d = 0.f;
            #pragma unroll
            for (int q = 0; q < 8; ++q) {
                float4 vv = v[q];
                o0a = fmaf(acc0[4*q+0], vv.x, o0a);
                o1a = fmaf(acc1[4*q+0], vv.x, o1a);
                o0b = fmaf(acc0[4*q+1], vv.y, o0b);
                o1b = fmaf(acc1[4*q+1], vv.y, o1b);
                o0c = fmaf(acc0[4*q+2], vv.z, o0c);
                o1c = fmaf(acc1[4*q+2], vv.z, o1c);
                o0d = fmaf(acc0[4*q+3], vv.w, o0d);
                o1d = fmaf(acc1[4*q+3], vv.w, o1d);
            }
            float cvn = lds[PRED_LEN * RANK + n];
            float2 o;
            o.x = (o0a + o0b) + (o0c + o0d) + cvn + mean0;
            o.y = (o1a + o1b) + (o1c + o1d) + cvn + mean1;
            *(float2*)(op + n * CHANNELS) = o;
        }
    }
}

// ---------------- launcher ---------------------------------------------------

extern "C" void kernel_launch(void* const* d_in, const int* in_sizes, int n_in,
                              void* d_out, int out_size, void* d_ws, size_t ws_size,
                              hipStream_t stream) {
    (void)in_sizes; (void)n_in; (void)out_size; (void)ws_size;
    const float* x    = (const float*)d_in[0];
    const float* A    = (const float*)d_in[1];
    const float* B    = (const float*)d_in[2];
    const float* bias = (const float*)d_in[3];
    float* out = (float*)d_out;
    float* ws  = (float*)d_ws;

    float* Wp   = ws + WS_WP;
    float* Vt   = ws + WS_VT;
    float* cvec = ws + WS_CVEC;

    k_prep<<<dim3(89), dim3(256), 0, stream>>>(A, B, bias, Wp, Vt, cvec);
    k_main<<<dim3(2, BATCH), dim3(256), 0, stream>>>(x, A, Wp, Vt, cvec, out);
}